// Round 14
// baseline (266.405 us; speedup 1.0000x reference)
//
#include <hip/hip_runtime.h>

// CombinedActorModel R18: actor-per-wave, register-resident fragments.
// R12b model revisited: 21 ds_read_b128/wave-tile = ~252 LDS-pipe cyc AND an
// lgkmcnt wait in front of every MFMA -- ~27us of the 58us kernel, on the
// critical path (VALUBusy stuck at 47%). R7/R8 couldn't fix it because 3
// actors x 7 frags = 84 VGPR > any allocator budget. Fix: ONE actor per wave
// -> 7 frags = 28 VGPR, loaded global->reg once (L2-hot), pinned. Zero frag
// ds_reads, zero staging, no frag LDS. The 3 actor-waves of a group combine
// through a small double-buffered LDS buffer + 1 barrier/tile; combine+store
// duty rotates (tt%3) across the group's waves. Block 384 = 2 groups x 3
// waves; TPB=8; grid 4096. Epilogue keeps R12b's LDS-compacted coalesced
// store (R17 proved direct scatter is worse). exp without max-sub (R17
// validated numerics).

typedef _Float16 half8   __attribute__((ext_vector_type(8)));
typedef __fp16   fp16x2  __attribute__((ext_vector_type(2)));
typedef float    floatx4 __attribute__((ext_vector_type(4)));

#define NFRAG 21                    // 3 actors * (4 stage1 + 2 stage2 + 1 stage3)
#define FRAG_HALFS (NFRAG * 512)    // 10752 halfs = 21504 B
#define TPB 8                       // tiles per block (tile = 32 elems: 2 groups x 16)
#define NGROUP 2                    // element-groups per block
#define NWAVES (NGROUP * 3)         // 6 waves = 384 threads

__global__ __launch_bounds__(256) void prep_frags(
    const float* __restrict__ Wmx, const float* __restrict__ bmx,
    const float* __restrict__ Wnx, const float* __restrict__ bnx,
    const float* __restrict__ Wmy, const float* __restrict__ bmy,
    const float* __restrict__ Wny, const float* __restrict__ bny,
    const float* __restrict__ Wmz, const float* __restrict__ bmz,
    const float* __restrict__ Wnz, const float* __restrict__ bnz,
    const float* __restrict__ Wlin, const float* __restrict__ blin,
    const float* __restrict__ Wout, const float* __restrict__ bout,
    _Float16* __restrict__ frag)
{
    int i = threadIdx.x + blockIdx.x * blockDim.x;
    if (i >= FRAG_HALFS) return;
    int f = i >> 9, rem = i & 511;
    int lane = rem >> 3, j = rem & 7;
    int q = lane >> 4, m = lane & 15;
    int a = f / 7, idx = f % 7;
    float v = 0.f;
    if (idx < 4) {
        int c = m + ((idx & 1) ? 16 : 0);
        int k = 8 * q + j;
        bool npart = (idx >= 2);
        if (c < 10) {
            if (!npart) { if (k < 6)             v = Wmx[(a*10 + c)*6 + k];
                          else if (k == 27)      v = bmx[a*10 + c]; }
            else        { if (k >= 6 && k < 9)   v = Wnx[(a*10 + c)*3 + (k-6)];
                          else if (k == 27)      v = bnx[a*10 + c]; }
        } else if (c < 20) {
            if (!npart) { if (k >= 9 && k < 15)  v = Wmy[(a*10 + c-10)*6 + (k-9)];
                          else if (k == 27)      v = bmy[a*10 + c-10]; }
            else        { if (k >= 15 && k < 18) v = Wny[(a*10 + c-10)*3 + (k-15)];
                          else if (k == 27)      v = bny[a*10 + c-10]; }
        } else if (c < 25) {
            if (!npart) { if (k >= 18 && k < 24) v = Wmz[(a*5 + c-20)*6 + (k-18)];
                          else if (k == 27)      v = bmz[a*5 + c-20]; }
            else        { if (k >= 24 && k < 27) v = Wnz[(a*5 + c-20)*3 + (k-24)];
                          else if (k == 27)      v = bnz[a*5 + c-20]; }
        }
    } else if (idx < 6) {
        int o  = m + ((idx == 5) ? 16 : 0);
        int kc = 16 * (j >> 2) + 4 * q + (j & 3);   // sigma(q,j)
        if (o < 25) {
            if (kc < 25)       v = Wlin[(a*25 + o)*25 + kc];
            else if (kc == 25) v = blin[a*25 + o];
        }
    } else {
        int ko = 16 * (j >> 2) + 4 * q + (j & 3);
        if (m < 10) {
            if (ko < 25)       v = Wout[(a*15 + m)*25 + ko];
            else if (ko == 25) v = bout[a*15 + m];
        }
    }
    frag[(size_t)f * 512 + lane * 8 + j] = (_Float16)v;
}

__global__ __launch_bounds__(64 * NWAVES) void actor_mfma(
    const float* __restrict__ spatial,
    const _Float16* __restrict__ frag,
    float* __restrict__ out)
{
    // combine buffer: [parity][(g*3+a)*16 + e][12]  (10 ch + 2 pad, 48B rows)
    __shared__ float comb[2][NGROUP * 3 * 16 * 12];   // 9216 B
    __shared__ float lds_o[NGROUP * 144];             // 1152 B, store compaction

    const int t = threadIdx.x;
    const int lane = t & 63, w = t >> 6;
    const int a = w % 3;            // this wave's actor
    const int g = w / 3;            // this wave's element-group
    const int q = lane >> 4, e = lane & 15;
    const size_t b0 = (size_t)blockIdx.x * (16 * NGROUP * TPB);

    // ---- this actor's 7 fragments: global -> VGPR once (L2-hot), pinned
    const _Float16* fbp = frag + (size_t)(a * 7) * 512 + lane * 8;
    half8 F[7];
    #pragma unroll
    for (int i = 0; i < 7; ++i) F[i] = *(const half8*)(fbp + i * 512);
    #pragma unroll
    for (int i = 0; i < 7; ++i) asm volatile("" : "+v"(F[i]));

    const float* sbase = spatial + (b0 + (size_t)(g * 16 + e)) * 27 + 8 * q;
    float* const ldso = lds_o + g * 144;
    const floatx4 z = {0.f, 0.f, 0.f, 0.f};

    union H8u { half8 v; fp16x2 p[4]; };

    auto loadT = [&](float (&dst)[8], int tt) {
        const float* s_ = sbase + (size_t)tt * (16 * NGROUP * 27);
        #pragma unroll
        for (int j = 0; j < 8; ++j) {
            int k = 8 * q + j;
            float v = (k == 27) ? 1.f : 0.f;   // bias slot; k>27 -> 0
            if (k < 27) v = s_[j];
            dst[j] = v;
        }
    };

    auto ss = [](float v_) {
        return v_ * __builtin_amdgcn_rcpf(1.0f + __builtin_fabsf(v_));
    };

    auto tileCompute = [&](const float (&cur)[8], int tt) {
        H8u Bs;
        #pragma unroll
        for (int p_ = 0; p_ < 4; ++p_)
            Bs.p[p_] = __builtin_amdgcn_cvt_pkrtz(cur[2*p_], cur[2*p_+1]);

        // ---- single-actor chain, all operands in registers
        H8u P;
        {
            floatx4 M0 = __builtin_amdgcn_mfma_f32_16x16x32_f16(F[0], Bs.v, z, 0,0,0);
            floatx4 N0 = __builtin_amdgcn_mfma_f32_16x16x32_f16(F[2], Bs.v, z, 0,0,0);
            P.p[0] = __builtin_amdgcn_cvt_pkrtz(M0[0]*N0[0], M0[1]*N0[1]);
            P.p[1] = __builtin_amdgcn_cvt_pkrtz(M0[2]*N0[2], M0[3]*N0[3]);
        }
        {
            floatx4 M1 = __builtin_amdgcn_mfma_f32_16x16x32_f16(F[1], Bs.v, z, 0,0,0);
            floatx4 N1 = __builtin_amdgcn_mfma_f32_16x16x32_f16(F[3], Bs.v, z, 0,0,0);
            float g5 = (q == 2) ? 1.f : M1[1]*N1[1];   // sigma slot kc=25: stage2 bias
            P.p[2] = __builtin_amdgcn_cvt_pkrtz(M1[0]*N1[0], g5);
            P.p[3] = __builtin_amdgcn_cvt_pkrtz(M1[2]*N1[2], M1[3]*N1[3]);
        }
        floatx4 H0 = __builtin_amdgcn_mfma_f32_16x16x32_f16(F[4], P.v, z, 0,0,0);
        floatx4 H1 = __builtin_amdgcn_mfma_f32_16x16x32_f16(F[5], P.v, z, 0,0,0);
        H8u Hh;
        Hh.p[0] = __builtin_amdgcn_cvt_pkrtz(ss(H0[0]), ss(H0[1]));
        Hh.p[1] = __builtin_amdgcn_cvt_pkrtz(ss(H0[2]), ss(H0[3]));
        float h5 = (q == 2) ? 1.f : ss(H1[1]);
        Hh.p[2] = __builtin_amdgcn_cvt_pkrtz(ss(H1[0]), h5);
        Hh.p[3] = __builtin_amdgcn_cvt_pkrtz(ss(H1[2]), ss(H1[3]));
        floatx4 oacc = __builtin_amdgcn_mfma_f32_16x16x32_f16(F[6], Hh.v, z, 0,0,0);
        // lane (e,q) reg r holds ch = 4q+r (ch8 @ q=2,r=0; gate ch9 @ q=2,r=1)

        // ---- publish to the group's combine buffer (parity-double-buffered)
        float* cw_ = &comb[tt & 1][((g * 3 + a) * 16 + e) * 12];
        if (q < 2) {
            *(float4*)(cw_ + 4 * q) = *(const float4*)&oacc;      // ch 4q..4q+3
        } else if (q == 2) {
            *(float2*)(cw_ + 8) = make_float2(oacc[0], oacc[1]);  // ch8, ch9
        }

        __syncthreads();

        // ---- rotating combine wave: softmax over actors + weighted sum + store
        if (a == tt % 3) {
            const float* cg = &comb[tt & 1][(g * 3) * 16 * 12];
            const float* r0 = cg + (e) * 12;
            const float* r1 = cg + (16 + e) * 12;
            const float* r2 = cg + (32 + e) * 12;
            float2 t0 = *(const float2*)(r0 + 8);   // (ch8, ch9) actor0
            float2 t1 = *(const float2*)(r1 + 8);
            float2 t2 = *(const float2*)(r2 + 8);
            float e0 = __expf(t0.y);
            float e1 = __expf(t1.y);
            float e2 = __expf(t2.y);
            float inv = __builtin_amdgcn_rcpf(e0 + e1 + e2);
            e0 *= inv; e1 *= inv; e2 *= inv;

            if (q < 2) {
                float4 v0 = *(const float4*)(r0 + 4 * q);
                float4 v1 = *(const float4*)(r1 + 4 * q);
                float4 v2 = *(const float4*)(r2 + 4 * q);
                ldso[e * 9 + 4 * q + 0] = v0.x * e0 + v1.x * e1 + v2.x * e2;
                ldso[e * 9 + 4 * q + 1] = v0.y * e0 + v1.y * e1 + v2.y * e2;
                ldso[e * 9 + 4 * q + 2] = v0.z * e0 + v1.z * e1 + v2.z * e2;
                ldso[e * 9 + 4 * q + 3] = v0.w * e0 + v1.w * e1 + v2.w * e2;
            } else if (q == 2) {
                ldso[e * 9 + 8] = t0.x * e0 + t1.x * e1 + t2.x * e2;
            }
            // same-wave DS ordering: writes retire before these reads issue
            if (lane < 36) {
                float4 v = *(const float4*)(ldso + lane * 4);
                *(float4*)(out + (b0 + (size_t)tt * (16 * NGROUP) + g * 16) * 9 + lane * 4) = v;
            }
        }
    };

    // ---- software-pipelined tile loop: prefetch 1 tile ahead, ping-pong regs
    float sA[8], sB[8];
    loadT(sA, 0);
    for (int tt = 0; tt < TPB; tt += 2) {
        loadT(sB, tt + 1);
        tileCompute(sA, tt);
        if (tt + 2 < TPB) loadT(sA, tt + 2);
        tileCompute(sB, tt + 1);
    }
}

extern "C" void kernel_launch(void* const* d_in, const int* in_sizes, int n_in,
                              void* d_out, int out_size, void* d_ws, size_t ws_size,
                              hipStream_t stream) {
    const float* spatial = (const float*)d_in[0];
    // d_in[1] = car_stats: unused by the model, never read.
    const float* Wmx  = (const float*)d_in[2];
    const float* bmx  = (const float*)d_in[3];
    const float* Wnx  = (const float*)d_in[4];
    const float* bnx  = (const float*)d_in[5];
    const float* Wmy  = (const float*)d_in[6];
    const float* bmy  = (const float*)d_in[7];
    const float* Wny  = (const float*)d_in[8];
    const float* bny  = (const float*)d_in[9];
    const float* Wmz  = (const float*)d_in[10];
    const float* bmz  = (const float*)d_in[11];
    const float* Wnz  = (const float*)d_in[12];
    const float* bnz  = (const float*)d_in[13];
    const float* Wlin = (const float*)d_in[14];
    const float* blin = (const float*)d_in[15];
    const float* Wout = (const float*)d_in[16];
    const float* bout = (const float*)d_in[17];
    float* out = (float*)d_out;

    _Float16* frag = (_Float16*)d_ws;   // 21504 B

    prep_frags<<<dim3(42), dim3(256), 0, stream>>>(
        Wmx, bmx, Wnx, bnx, Wmy, bmy, Wny, bny, Wmz, bmz, Wnz, bnz,
        Wlin, blin, Wout, bout, frag);

    const int nb = in_sizes[0] / 27;           // 1048576, multiple of 16*NGROUP*TPB
    dim3 grid(nb / (16 * NGROUP * TPB));       // 4096 blocks, 6 waves each
    actor_mfma<<<grid, dim3(64 * NWAVES), 0, stream>>>(spatial, frag, out);
}